// Round 1
// baseline (1436.187 us; speedup 1.0000x reference)
//
#include <hip/hip_runtime.h>
#include <hip/hip_bf16.h>

#define NTOK 4096
#define DM   1024
#define DF   4096
#define ROWS_TOTAL 12288   // 4096 shared + 4096*2 routed (top-2, always exactly 2)
#define BM 128
#define BN 128
#define BK 64
#define LDK 72             // +8 bf16 pad -> 2-way LDS bank aliasing only (free)

typedef __attribute__((ext_vector_type(8))) short short8;
typedef __attribute__((ext_vector_type(4))) float floatx4;

__device__ __forceinline__ ushort f2bf(float f){
    __hip_bfloat16 h = __float2bfloat16(f);
    return *reinterpret_cast<ushort*>(&h);
}

__device__ __forceinline__ float gelu_tanh(float x){
    // JAX default gelu (approximate=True)
    float u = 0.7978845608028654f * (x + 0.044715f * x * x * x);
    return 0.5f * x * (1.0f + tanhf(u));
}

__global__ __launch_bounds__(256) void cvt_kernel(const float* __restrict__ src,
                                                  ushort* __restrict__ dst, int n4){
    int i = blockIdx.x * 256 + threadIdx.x;
    if (i < n4){
        float4 v = reinterpret_cast<const float4*>(src)[i];
        ushort4 o = { f2bf(v.x), f2bf(v.y), f2bf(v.z), f2bf(v.w) };
        reinterpret_cast<ushort4*>(dst)[i] = o;
    }
}

// one wave per token: fp32 logits -> softmax -> top2 (strict >, lowest index wins ties, matching lax.top_k)
__global__ __launch_bounds__(256) void router_kernel(
    const float* __restrict__ x, const float* __restrict__ wr,
    int* __restrict__ counts, int* __restrict__ te, float* __restrict__ tg,
    int* __restrict__ tokarr, float* __restrict__ gatearr)
{
    const int token = blockIdx.x * 4 + (threadIdx.x >> 6);
    const int lane  = threadIdx.x & 63;
    const float* xp = x + (size_t)token * DM;
    float s[8];
    #pragma unroll
    for (int e = 0; e < 8; e++) s[e] = 0.f;
    for (int d = lane; d < DM; d += 64){
        float xv = xp[d];
        #pragma unroll
        for (int e = 0; e < 8; e++) s[e] += xv * wr[e * DM + d];
    }
    #pragma unroll
    for (int e = 0; e < 8; e++){
        float v = s[e];
        #pragma unroll
        for (int off = 32; off > 0; off >>= 1) v += __shfl_down(v, off);
        s[e] = v;   // lane 0 holds the full sum
    }
    if (lane == 0){
        float m = s[0];
        #pragma unroll
        for (int e = 1; e < 8; e++) m = fmaxf(m, s[e]);
        float p[8]; float sum = 0.f;
        #pragma unroll
        for (int e = 0; e < 8; e++){ p[e] = __expf(s[e] - m); sum += p[e]; }
        float inv = 1.f / sum;
        #pragma unroll
        for (int e = 0; e < 8; e++) p[e] *= inv;
        int i1 = 0; float p1 = p[0];
        #pragma unroll
        for (int e = 1; e < 8; e++) if (p[e] > p1){ p1 = p[e]; i1 = e; }
        int i2 = -1; float p2 = -1.f;
        #pragma unroll
        for (int e = 0; e < 8; e++) if (e != i1 && p[e] > p2){ p2 = p[e]; i2 = e; }
        atomicAdd(&counts[i1], 1);
        atomicAdd(&counts[i2], 1);
        te[token*2+0] = i1; te[token*2+1] = i2;
        tg[token*2+0] = p1; tg[token*2+1] = p2;
        // shared-expert rows are the identity mapping, gate = SCALE
        tokarr[token]  = token;
        gatearr[token] = 0.8944271909999159f;
    }
}

__global__ void scan_kernel(int* counts, int* rowbase, int* cursor){
    if (threadIdx.x == 0 && blockIdx.x == 0){
        int off = NTOK;
        for (int e = 0; e < 8; e++){ rowbase[e] = off; cursor[e] = off; off += counts[e]; }
        rowbase[8] = 0;      // shared expert
        counts[8]  = NTOK;
    }
}

__global__ __launch_bounds__(256) void fill_kernel(
    const int* __restrict__ te, const float* __restrict__ tg,
    int* cursor, int* tokarr, float* gatearr)
{
    int token = blockIdx.x * 256 + threadIdx.x;
    #pragma unroll
    for (int j = 0; j < 2; j++){
        int e   = te[token*2+j];
        float g = tg[token*2+j];
        int p = atomicAdd(&cursor[e], 1);
        tokarr[p]  = token;
        gatearr[p] = 0.8944271909999159f * g;
    }
}

// MODE 0: H[row] = gelu(Xg @ W1_e^T + b1_e)          (M=rows, N=4096, K=1024)
// MODE 1: out[tok[row]] += gate[row]*(H @ W2_e^T + b2_e)  (M=rows, N=1024, K=4096)
// blockIdx.x = e*32 + mtile (e in 0..8, 8 == shared); blockIdx.y = ntile
template<int MODE>
__global__ __launch_bounds__(256) void gemm_kernel(
    const ushort* __restrict__ Abase,
    const ushort* __restrict__ Wb,      // routed expert weights, expert stride DF*DM
    const ushort* __restrict__ Wsb,     // shared expert weights
    const float* __restrict__ brout,    // b1 or b2, [8][N]
    const float* __restrict__ bsh,      // bs1 or bs2, [N]
    const int* __restrict__ counts, const int* __restrict__ rowbase,
    const int* __restrict__ tokarr, const float* __restrict__ gatearr,
    ushort* __restrict__ Hout, float* __restrict__ out)
{
    const int e   = blockIdx.x >> 5;
    const int mt  = blockIdx.x & 31;
    const int nt  = blockIdx.y;
    const int cnt = counts[e];
    if (mt * BM >= cnt) return;
    const int base = rowbase[e];
    const int K = (MODE == 0) ? DM : DF;
    const ushort* Bp  = (e < 8) ? (Wb + (size_t)e * DF * DM) : Wsb;
    const float* bias = (e < 8) ? (brout + e * ((MODE == 0) ? DF : DM)) : bsh;

    __shared__ ushort As[BM * LDK];
    __shared__ ushort Bs[BN * LDK];

    const int t    = threadIdx.x;
    const int lane = t & 63;
    const int wv   = t >> 6;
    const int wm   = (wv >> 1) * 64;
    const int wn   = (wv & 1) * 64;
    const int lrow = lane & 15;
    const int quad = lane >> 4;

    // staging map: chunk c = i*256 + t ; row = c>>3 (0..127) ; 16B seg = c&7
    const ushort* Asrc[4];
    #pragma unroll
    for (int i = 0; i < 4; i++){
        int s   = (t >> 3) + 32 * i;
        int pos = mt * BM + s;
        int clp = (pos < cnt) ? pos : 0;                 // clamp: results discarded anyway
        if (MODE == 0){
            int tk = tokarr[base + clp];
            Asrc[i] = Abase + (size_t)tk * DM;
        } else {
            Asrc[i] = Abase + (size_t)(base + clp) * DF;
        }
    }
    const ushort* Bsrc[4];
    #pragma unroll
    for (int i = 0; i < 4; i++){
        int n = nt * BN + (t >> 3) + 32 * i;
        Bsrc[i] = Bp + (size_t)n * K;
    }
    const int segoff = (t & 7) * 8;

    floatx4 acc[4][4];
    #pragma unroll
    for (int mi = 0; mi < 4; mi++)
        #pragma unroll
        for (int ni = 0; ni < 4; ni++)
            acc[mi][ni] = (floatx4){0.f, 0.f, 0.f, 0.f};

    for (int k0 = 0; k0 < K; k0 += BK){
        __syncthreads();
        #pragma unroll
        for (int i = 0; i < 4; i++){
            int row = (t >> 3) + 32 * i;
            uint4 va = *reinterpret_cast<const uint4*>(Asrc[i] + k0 + segoff);
            *reinterpret_cast<uint4*>(&As[row * LDK + segoff]) = va;
            uint4 vb = *reinterpret_cast<const uint4*>(Bsrc[i] + k0 + segoff);
            *reinterpret_cast<uint4*>(&Bs[row * LDK + segoff]) = vb;
        }
        __syncthreads();
        #pragma unroll
        for (int kk = 0; kk < BK; kk += 32){
            short8 af[4], bfr[4];
            #pragma unroll
            for (int mi = 0; mi < 4; mi++)
                af[mi] = *reinterpret_cast<const short8*>(&As[(wm + mi*16 + lrow) * LDK + kk + quad*8]);
            #pragma unroll
            for (int ni = 0; ni < 4; ni++)
                bfr[ni] = *reinterpret_cast<const short8*>(&Bs[(wn + ni*16 + lrow) * LDK + kk + quad*8]);
            #pragma unroll
            for (int mi = 0; mi < 4; mi++)
                #pragma unroll
                for (int ni = 0; ni < 4; ni++)
                    acc[mi][ni] = __builtin_amdgcn_mfma_f32_16x16x32_bf16(af[mi], bfr[ni], acc[mi][ni], 0, 0, 0);
        }
    }

    // epilogue; C/D layout: col = lane&15, row = quad*4 + reg   [m89-verified]
    float bv[4];
    #pragma unroll
    for (int ni = 0; ni < 4; ni++) bv[ni] = bias[nt * BN + wn + ni*16 + lrow];

    #pragma unroll
    for (int mi = 0; mi < 4; mi++){
        #pragma unroll
        for (int r = 0; r < 4; r++){
            int s   = wm + mi*16 + quad*4 + r;
            int pos = mt * BM + s;
            if (pos >= cnt) continue;          // never write another expert's rows
            int rr = base + pos;
            if (MODE == 0){
                ushort* hp = Hout + (size_t)rr * DF + nt * BN;
                #pragma unroll
                for (int ni = 0; ni < 4; ni++){
                    float v = acc[mi][ni][r] + bv[ni];
                    hp[wn + ni*16 + lrow] = f2bf(gelu_tanh(v));
                }
            } else {
                int tk  = tokarr[rr];
                float g = gatearr[rr];
                float* op = out + (size_t)tk * DM + nt * BN;
                #pragma unroll
                for (int ni = 0; ni < 4; ni++){
                    float v = acc[mi][ni][r] + bv[ni];
                    atomicAdd(op + wn + ni*16 + lrow, g * v);
                }
            }
        }
    }
}

extern "C" void kernel_launch(void* const* d_in, const int* in_sizes, int n_in,
                              void* d_out, int out_size, void* d_ws, size_t ws_size,
                              hipStream_t stream) {
    const float* x   = (const float*)d_in[0];
    const float* wr  = (const float*)d_in[1];
    const float* W1  = (const float*)d_in[2];
    const float* b1  = (const float*)d_in[3];
    const float* W2  = (const float*)d_in[4];
    const float* b2  = (const float*)d_in[5];
    const float* Ws1 = (const float*)d_in[6];
    const float* bs1 = (const float*)d_in[7];
    const float* Ws2 = (const float*)d_in[8];
    const float* bs2 = (const float*)d_in[9];
    float* out = (float*)d_out;

    char* ws = (char*)d_ws;
    size_t off = 0;
    auto wsalloc = [&](size_t bytes) -> char* {
        char* p = ws + off;
        off += (bytes + 255) & ~(size_t)255;
        return p;
    };
    ushort* xb      = (ushort*)wsalloc((size_t)NTOK * DM * 2);        //   8.4 MB
    ushort* w1b     = (ushort*)wsalloc((size_t)8 * DF * DM * 2);      //  67.1 MB
    ushort* w2b     = (ushort*)wsalloc((size_t)8 * DM * DF * 2);      //  67.1 MB
    ushort* ws1b    = (ushort*)wsalloc((size_t)DF * DM * 2);          //   8.4 MB
    ushort* ws2b    = (ushort*)wsalloc((size_t)DM * DF * 2);          //   8.4 MB
    ushort* H       = (ushort*)wsalloc((size_t)ROWS_TOTAL * DF * 2);  // 100.7 MB
    int*    tokarr  = (int*)  wsalloc(ROWS_TOTAL * 4);
    float*  gatearr = (float*)wsalloc(ROWS_TOTAL * 4);
    int*    te      = (int*)  wsalloc(NTOK * 2 * 4);
    float*  tg      = (float*)wsalloc(NTOK * 2 * 4);
    int*    counts  = (int*)  wsalloc(16 * 4);
    int*    rowbase = (int*)  wsalloc(16 * 4);
    int*    cursor  = (int*)  wsalloc(16 * 4);

    hipMemsetAsync(out, 0, (size_t)NTOK * DM * sizeof(float), stream);
    hipMemsetAsync(counts, 0, 16 * 4, stream);

    cvt_kernel<<<(NTOK*DM/4   + 255)/256, 256, 0, stream>>>(x,   xb,   NTOK*DM/4);
    cvt_kernel<<<(8*DF*DM/4   + 255)/256, 256, 0, stream>>>(W1,  w1b,  8*DF*DM/4);
    cvt_kernel<<<(8*DM*DF/4   + 255)/256, 256, 0, stream>>>(W2,  w2b,  8*DM*DF/4);
    cvt_kernel<<<(DF*DM/4     + 255)/256, 256, 0, stream>>>(Ws1, ws1b, DF*DM/4);
    cvt_kernel<<<(DM*DF/4     + 255)/256, 256, 0, stream>>>(Ws2, ws2b, DM*DF/4);

    router_kernel<<<NTOK/4, 256, 0, stream>>>(x, wr, counts, te, tg, tokarr, gatearr);
    scan_kernel<<<1, 1, 0, stream>>>(counts, rowbase, cursor);
    fill_kernel<<<NTOK/256, 256, 0, stream>>>(te, tg, cursor, tokarr, gatearr);

    // expert-parallel grouped GEMMs: 9 experts x 32 m-tiles, early-exit past count
    gemm_kernel<0><<<dim3(9*32, DF/BN), 256, 0, stream>>>(xb, w1b, ws1b, b1, bs1,
        counts, rowbase, tokarr, gatearr, H, out);
    gemm_kernel<1><<<dim3(9*32, DM/BN), 256, 0, stream>>>(H, w2b, ws2b, b2, bs2,
        counts, rowbase, tokarr, gatearr, H, out);
}

// Round 2
// 886.621 us; speedup vs baseline: 1.6198x; 1.6198x over previous
//
#include <hip/hip_runtime.h>
#include <hip/hip_bf16.h>

#define NTOK 4096
#define DM   1024
#define DF   4096
#define ROWS_TOTAL 12288   // 4096 shared + 8192 routed (top-2)
#define BM 128
#define BN 128
#define BK 64
#define TILES_MAX 112      // worst case: 32 shared + 71 routed m-tiles
#define SCALE_F 0.8944271909999159f

typedef __attribute__((ext_vector_type(8))) short short8;
typedef __attribute__((ext_vector_type(4))) float floatx4;

// async global->LDS, 16B/lane; LDS dest = wave-uniform base + lane*16 (m97/m104)
#define GLD16(gp, lp) __builtin_amdgcn_global_load_lds( \
    (const __attribute__((address_space(1))) void*)(gp), \
    (__attribute__((address_space(3))) void*)(lp), 16, 0, 0)

__device__ __forceinline__ ushort f2bf(float f){
    __hip_bfloat16 h = __float2bfloat16(f);
    return *reinterpret_cast<ushort*>(&h);
}

__device__ __forceinline__ float gelu_tanh(float x){
    float u = 0.7978845608028654f * (x + 0.044715f * x * x * x);
    return 0.5f * x * (1.0f + tanhf(u));
}

__global__ __launch_bounds__(256) void cvt_kernel(const float* __restrict__ src,
                                                  ushort* __restrict__ dst, int n4){
    int i = blockIdx.x * 256 + threadIdx.x;
    if (i < n4){
        float4 v = reinterpret_cast<const float4*>(src)[i];
        ushort4 o = { f2bf(v.x), f2bf(v.y), f2bf(v.z), f2bf(v.w) };
        reinterpret_cast<ushort4*>(dst)[i] = o;
    }
}

// one wave per token: fp32 logits -> top2 (selection monotone in logits)
__global__ __launch_bounds__(256) void router_kernel(
    const float* __restrict__ x, const float* __restrict__ wr,
    int* __restrict__ counts, int* __restrict__ te, float* __restrict__ tg,
    int* __restrict__ tokarr)
{
    const int token = blockIdx.x * 4 + (threadIdx.x >> 6);
    const int lane  = threadIdx.x & 63;
    const float* xp = x + (size_t)token * DM;
    float s[8];
    #pragma unroll
    for (int e = 0; e < 8; e++) s[e] = 0.f;
    for (int d = lane; d < DM; d += 64){
        float xv = xp[d];
        #pragma unroll
        for (int e = 0; e < 8; e++) s[e] += xv * wr[e * DM + d];
    }
    #pragma unroll
    for (int e = 0; e < 8; e++){
        float v = s[e];
        #pragma unroll
        for (int off = 32; off > 0; off >>= 1) v += __shfl_down(v, off);
        s[e] = v;
    }
    if (lane == 0){
        float m = s[0];
        #pragma unroll
        for (int e = 1; e < 8; e++) m = fmaxf(m, s[e]);
        float p[8]; float sum = 0.f;
        #pragma unroll
        for (int e = 0; e < 8; e++){ p[e] = __expf(s[e] - m); sum += p[e]; }
        float inv = 1.f / sum;
        #pragma unroll
        for (int e = 0; e < 8; e++) p[e] *= inv;
        int i1 = 0; float p1 = p[0];
        #pragma unroll
        for (int e = 1; e < 8; e++) if (p[e] > p1){ p1 = p[e]; i1 = e; }
        int i2 = -1; float p2 = -1.f;
        #pragma unroll
        for (int e = 0; e < 8; e++) if (e != i1 && p[e] > p2){ p2 = p[e]; i2 = e; }
        atomicAdd(&counts[i1], 1);
        atomicAdd(&counts[i2], 1);
        te[token*2+0] = i1; te[token*2+1] = i2;
        tg[token*2+0] = p1; tg[token*2+1] = p2;
        tokarr[token] = token;      // shared-expert rows = identity
    }
}

__global__ void scan_kernel(int* counts, int* rowbase, int* cursor, int* tiles){
    if (threadIdx.x == 0 && blockIdx.x == 0){
        int off = NTOK;
        for (int e = 0; e < 8; e++){ rowbase[e] = off; cursor[e] = off; off += counts[e]; }
        rowbase[8] = 0;
        counts[8]  = NTOK;
        int idx = 0;
        for (int e = 0; e < 9; e++){
            int c = counts[e];
            for (int mt = 0; mt * BM < c && idx < TILES_MAX; mt++)
                tiles[idx++] = (e << 8) | mt;
        }
        for (; idx < TILES_MAX; idx++) tiles[idx] = -1;
    }
}

__global__ __launch_bounds__(256) void fill_kernel(
    const int* __restrict__ te, int* cursor, int* tokarr, int* rowof)
{
    int token = blockIdx.x * 256 + threadIdx.x;
    #pragma unroll
    for (int j = 0; j < 2; j++){
        int e = te[token*2+j];
        int p = atomicAdd(&cursor[e], 1);
        tokarr[p] = token;
        rowof[token*2+j] = p;
    }
}

// MODE 0: H[row] = gelu(Xg @ W1_e^T + b1)   (N=4096, K=1024) -> bf16 H
// MODE 1: Y[row] = H @ W2_e^T + b2          (N=1024, K=4096) -> fp32 Y
template<int MODE>
__global__ __launch_bounds__(256) void gemm_kernel(
    const ushort* __restrict__ Abase,
    const ushort* __restrict__ Wb, const ushort* __restrict__ Wsb,
    const float* __restrict__ brout, const float* __restrict__ bsh,
    const int* __restrict__ counts, const int* __restrict__ rowbase,
    const int* __restrict__ tokarr, const int* __restrict__ tiles,
    ushort* __restrict__ Hout, float* __restrict__ Yout)
{
    const int tile = tiles[blockIdx.x];
    if (tile < 0) return;
    const int e  = tile >> 8;
    const int mt = tile & 255;
    const int nt = blockIdx.y;
    const int cnt  = counts[e];
    const int base = rowbase[e];
    const int K = (MODE == 0) ? DM : DF;
    const int N = (MODE == 0) ? DF : DM;
    const ushort* Bp  = (e < 8) ? (Wb + (size_t)e * DF * DM) : Wsb;
    const float* bias = (e < 8) ? (brout + e * N) : bsh;

    __shared__ ushort As[BM * BK];   // unpadded: required by global_load_lds
    __shared__ ushort Bs[BN * BK];

    const int t    = threadIdx.x;
    const int lane = t & 63;
    const int wv   = t >> 6;
    const int wm   = (wv >> 1) * 64;
    const int wn   = (wv & 1) * 64;
    const int lrow = lane & 15;
    const int quad = lane >> 4;
    // column swizzle (units of 8 ushorts = 16B): phys_seg = log_seg ^ (row&7)
    const int swz8 = ((lane & 7) ^ (lane >> 3)) * 8;

    // wave wv stages tile rows [wv*32, wv*32+32), 4 insts x 8 rows
    const ushort* Ap[4];
    const ushort* Bpp[4];
    ushort* Alds[4];
    ushort* Blds[4];
    #pragma unroll
    for (int i = 0; i < 4; i++){
        int rin = wv * 32 + i * 8 + (lane >> 3);
        int pos = mt * BM + rin;
        int clp = (pos < cnt) ? pos : (cnt - 1);
        if (MODE == 0) Ap[i] = Abase + (size_t)tokarr[base + clp] * DM + swz8;
        else           Ap[i] = Abase + (size_t)(base + clp) * DF + swz8;
        Bpp[i]  = Bp + (size_t)(nt * BN + rin) * K + swz8;
        Alds[i] = &As[(wv * 32 + i * 8) * BK];
        Blds[i] = &Bs[(wv * 32 + i * 8) * BK];
    }

    floatx4 acc[4][4];
    #pragma unroll
    for (int mi = 0; mi < 4; mi++)
        #pragma unroll
        for (int ni = 0; ni < 4; ni++)
            acc[mi][ni] = (floatx4){0.f, 0.f, 0.f, 0.f};

    for (int k0 = 0; k0 < K; k0 += BK){
        __syncthreads();
        #pragma unroll
        for (int i = 0; i < 4; i++){
            GLD16(Ap[i]  + k0, Alds[i]);
            GLD16(Bpp[i] + k0, Blds[i]);
        }
        __syncthreads();   // vmcnt(0) drain + barrier (m97 structure)
        #pragma unroll
        for (int kk = 0; kk < BK; kk += 32){
            short8 af[4], bfr[4];
            #pragma unroll
            for (int mi = 0; mi < 4; mi++){
                int row  = wm + mi * 16 + lrow;
                int phys = ((kk >> 3) + quad) ^ (row & 7);
                af[mi] = *reinterpret_cast<const short8*>(&As[row * BK + phys * 8]);
            }
            #pragma unroll
            for (int ni = 0; ni < 4; ni++){
                int row  = wn + ni * 16 + lrow;
                int phys = ((kk >> 3) + quad) ^ (row & 7);
                bfr[ni] = *reinterpret_cast<const short8*>(&Bs[row * BK + phys * 8]);
            }
            #pragma unroll
            for (int mi = 0; mi < 4; mi++)
                #pragma unroll
                for (int ni = 0; ni < 4; ni++)
                    acc[mi][ni] = __builtin_amdgcn_mfma_f32_16x16x32_bf16(af[mi], bfr[ni], acc[mi][ni], 0, 0, 0);
        }
    }

    // epilogue; C/D: col = lane&15, row = quad*4 + reg  [m89]
    float bv[4];
    #pragma unroll
    for (int ni = 0; ni < 4; ni++) bv[ni] = bias[nt * BN + wn + ni*16 + lrow];

    #pragma unroll
    for (int mi = 0; mi < 4; mi++){
        #pragma unroll
        for (int r = 0; r < 4; r++){
            int s   = wm + mi*16 + quad*4 + r;
            int pos = mt * BM + s;
            if (pos >= cnt) continue;
            int rr = base + pos;
            if (MODE == 0){
                ushort* hp = Hout + (size_t)rr * DF + nt * BN;
                #pragma unroll
                for (int ni = 0; ni < 4; ni++){
                    float v = acc[mi][ni][r] + bv[ni];
                    hp[wn + ni*16 + lrow] = f2bf(gelu_tanh(v));
                }
            } else {
                float* yp = Yout + (size_t)rr * DM + nt * BN;
                #pragma unroll
                for (int ni = 0; ni < 4; ni++)
                    yp[wn + ni*16 + lrow] = acc[mi][ni][r] + bv[ni];
            }
        }
    }
}

// out[t] = SCALE * (Y[t] + g1*Y[r1] + g2*Y[r2])
__global__ __launch_bounds__(256) void combine_kernel(
    const float* __restrict__ Y, const int* __restrict__ rowof,
    const float* __restrict__ tg, float* __restrict__ out)
{
    const int token = blockIdx.x;
    const int d4    = threadIdx.x;
    const float4* Y4 = reinterpret_cast<const float4*>(Y);
    int r1 = rowof[token*2+0], r2 = rowof[token*2+1];
    float g1 = tg[token*2+0],  g2 = tg[token*2+1];
    float4 a = Y4[(size_t)token * 256 + d4];
    float4 b = Y4[(size_t)r1 * 256 + d4];
    float4 c = Y4[(size_t)r2 * 256 + d4];
    float4 o;
    o.x = SCALE_F * (a.x + g1*b.x + g2*c.x);
    o.y = SCALE_F * (a.y + g1*b.y + g2*c.y);
    o.z = SCALE_F * (a.z + g1*b.z + g2*c.z);
    o.w = SCALE_F * (a.w + g1*b.w + g2*c.w);
    reinterpret_cast<float4*>(out)[(size_t)token * 256 + d4] = o;
}

extern "C" void kernel_launch(void* const* d_in, const int* in_sizes, int n_in,
                              void* d_out, int out_size, void* d_ws, size_t ws_size,
                              hipStream_t stream) {
    const float* x   = (const float*)d_in[0];
    const float* wr  = (const float*)d_in[1];
    const float* W1  = (const float*)d_in[2];
    const float* b1  = (const float*)d_in[3];
    const float* W2  = (const float*)d_in[4];
    const float* b2  = (const float*)d_in[5];
    const float* Ws1 = (const float*)d_in[6];
    const float* bs1 = (const float*)d_in[7];
    const float* Ws2 = (const float*)d_in[8];
    const float* bs2 = (const float*)d_in[9];
    float* out = (float*)d_out;

    char* ws = (char*)d_ws;
    size_t off = 0;
    auto wsalloc = [&](size_t bytes) -> char* {
        char* p = ws + off;
        off += (bytes + 255) & ~(size_t)255;
        return p;
    };
    ushort* xb   = (ushort*)wsalloc((size_t)NTOK * DM * 2);
    ushort* w1b  = (ushort*)wsalloc((size_t)8 * DF * DM * 2);
    ushort* w2b  = (ushort*)wsalloc((size_t)8 * DM * DF * 2);
    ushort* ws1b = (ushort*)wsalloc((size_t)DF * DM * 2);
    ushort* ws2b = (ushort*)wsalloc((size_t)DM * DF * 2);
    ushort* H    = (ushort*)wsalloc((size_t)ROWS_TOTAL * DF * 2);
    int*    tokarr = (int*)wsalloc(ROWS_TOTAL * 4);
    int*    rowof  = (int*)wsalloc(NTOK * 2 * 4);
    int*    te     = (int*)wsalloc(NTOK * 2 * 4);
    float*  tg     = (float*)wsalloc(NTOK * 2 * 4);
    int*    counts = (int*)wsalloc(16 * 4);
    int*    rowbase= (int*)wsalloc(16 * 4);
    int*    cursor = (int*)wsalloc(16 * 4);
    int*    tiles  = (int*)wsalloc(TILES_MAX * 4);
    // Y (50.3MB fp32) aliases w1b (67MB): w1b dead after gemm1, Y born in gemm2
    float*  Y = (float*)w1b;

    hipMemsetAsync(counts, 0, 16 * 4, stream);

    cvt_kernel<<<(NTOK*DM/4 + 255)/256, 256, 0, stream>>>(x,   xb,   NTOK*DM/4);
    cvt_kernel<<<(8*DF*DM/4 + 255)/256, 256, 0, stream>>>(W1,  w1b,  8*DF*DM/4);
    cvt_kernel<<<(8*DM*DF/4 + 255)/256, 256, 0, stream>>>(W2,  w2b,  8*DM*DF/4);
    cvt_kernel<<<(DF*DM/4   + 255)/256, 256, 0, stream>>>(Ws1, ws1b, DF*DM/4);
    cvt_kernel<<<(DM*DF/4   + 255)/256, 256, 0, stream>>>(Ws2, ws2b, DM*DF/4);

    router_kernel<<<NTOK/4, 256, 0, stream>>>(x, wr, counts, te, tg, tokarr);
    scan_kernel<<<1, 1, 0, stream>>>(counts, rowbase, cursor, tiles);
    fill_kernel<<<NTOK/256, 256, 0, stream>>>(te, cursor, tokarr, rowof);

    gemm_kernel<0><<<dim3(TILES_MAX, DF/BN), 256, 0, stream>>>(xb, w1b, ws1b, b1, bs1,
        counts, rowbase, tokarr, tiles, H, Y);
    gemm_kernel<1><<<dim3(TILES_MAX, DM/BN), 256, 0, stream>>>(H, w2b, ws2b, b2, bs2,
        counts, rowbase, tokarr, tiles, H, Y);

    combine_kernel<<<NTOK, 256, 0, stream>>>(Y, rowof, tg, out);
}

// Round 3
// 722.080 us; speedup vs baseline: 1.9890x; 1.2279x over previous
//
#include <hip/hip_runtime.h>
#include <hip/hip_bf16.h>

#define NTOK 4096
#define DM   1024
#define DF   4096
#define ROWS_TOTAL 12288   // 4096 shared + 8192 routed (top-2)
#define BM 128
#define BN 128
#define BK 64
#define SCALE_F 0.8944271909999159f
// worst-case sum of m-tiles over 9 experts: 32 (shared) + 71 (routed) = 103
#define PMAX 103

typedef __attribute__((ext_vector_type(8))) short short8;
typedef __attribute__((ext_vector_type(4))) float floatx4;

// async global->LDS, 16B/lane; LDS dest = wave-uniform base + lane*16 (m97/m104)
#define GLD16(gp, lp) __builtin_amdgcn_global_load_lds( \
    (const __attribute__((address_space(1))) void*)(gp), \
    (__attribute__((address_space(3))) void*)(lp), 16, 0, 0)

__device__ __forceinline__ ushort f2bf(float f){
    __hip_bfloat16 h = __float2bfloat16(f);
    return *reinterpret_cast<ushort*>(&h);
}

// 0.5x(1+tanh(u)) == x * sigmoid(2u), exp-form: ~6 VALU vs ~50 for tanhf
__device__ __forceinline__ float gelu_tanh(float v){
    float u2 = -1.5957691216057308f * (v + 0.044715f * v * v * v);
    return v / (1.0f + __expf(u2));
}

// one fused bf16-convert over all 5 fp32 arrays (in float4 units)
#define CVT_N0 1048576u            // x        : 4096*1024/4
#define CVT_N1 9437184u            // + W1     : 8*4096*1024/4
#define CVT_N2 17825792u           // + W2
#define CVT_N3 18874368u           // + Ws1
#define CVT_N4 19922944u           // + Ws2  (total; grid = total/256 = 77824)
__global__ __launch_bounds__(256) void cvt_all(
    const float* __restrict__ x,  const float* __restrict__ W1,
    const float* __restrict__ W2, const float* __restrict__ Ws1,
    const float* __restrict__ Ws2,
    ushort* __restrict__ xb,  ushort* __restrict__ w1b, ushort* __restrict__ w2b,
    ushort* __restrict__ ws1b, ushort* __restrict__ ws2b)
{
    unsigned i = blockIdx.x * 256u + threadIdx.x;
    const float* s; ushort* d; unsigned off;
    if      (i < CVT_N0){ s = x;   d = xb;   off = i; }
    else if (i < CVT_N1){ s = W1;  d = w1b;  off = i - CVT_N0; }
    else if (i < CVT_N2){ s = W2;  d = w2b;  off = i - CVT_N1; }
    else if (i < CVT_N3){ s = Ws1; d = ws1b; off = i - CVT_N2; }
    else                { s = Ws2; d = ws2b; off = i - CVT_N3; }
    float4 v = reinterpret_cast<const float4*>(s)[off];
    ushort4 o = { f2bf(v.x), f2bf(v.y), f2bf(v.z), f2bf(v.w) };
    reinterpret_cast<ushort4*>(d)[off] = o;
}

// one wave per token: fp32 logits -> softmax -> top2
__global__ __launch_bounds__(256) void router_kernel(
    const float* __restrict__ x, const float* __restrict__ wr,
    int* __restrict__ te, float* __restrict__ tg, int* __restrict__ tokarr)
{
    const int token = blockIdx.x * 4 + (threadIdx.x >> 6);
    const int lane  = threadIdx.x & 63;
    const float* xp = x + (size_t)token * DM;
    float s[8];
    #pragma unroll
    for (int e = 0; e < 8; e++) s[e] = 0.f;
    for (int d = lane; d < DM; d += 64){
        float xv = xp[d];
        #pragma unroll
        for (int e = 0; e < 8; e++) s[e] += xv * wr[e * DM + d];
    }
    #pragma unroll
    for (int e = 0; e < 8; e++){
        float v = s[e];
        #pragma unroll
        for (int off = 32; off > 0; off >>= 1) v += __shfl_down(v, off);
        s[e] = v;
    }
    if (lane == 0){
        float m = s[0];
        #pragma unroll
        for (int e = 1; e < 8; e++) m = fmaxf(m, s[e]);
        float p[8]; float sum = 0.f;
        #pragma unroll
        for (int e = 0; e < 8; e++){ p[e] = __expf(s[e] - m); sum += p[e]; }
        float inv = 1.f / sum;
        #pragma unroll
        for (int e = 0; e < 8; e++) p[e] *= inv;
        int i1 = 0; float p1 = p[0];
        #pragma unroll
        for (int e = 1; e < 8; e++) if (p[e] > p1){ p1 = p[e]; i1 = e; }
        int i2 = -1; float p2 = -1.f;
        #pragma unroll
        for (int e = 0; e < 8; e++) if (e != i1 && p[e] > p2){ p2 = p[e]; i2 = e; }
        te[token*2+0] = i1; te[token*2+1] = i2;
        tg[token*2+0] = p1; tg[token*2+1] = p2;
        tokarr[token] = token;      // shared-expert rows = identity
    }
}

// single 256-thread block: counts -> prefix/meta -> scatter routed rows.
// meta layout: [0..8]=counts, [16..24]=rowbase, [32..40]=mtiles
__global__ __launch_bounds__(256) void plan_kernel(
    const int* __restrict__ te, int* __restrict__ tokarr,
    int* __restrict__ rowof, int* __restrict__ meta)
{
    __shared__ int lc[9], lcur[9];
    const int t = threadIdx.x;
    if (t < 9) lc[t] = 0;
    __syncthreads();
    for (int j = t; j < NTOK*2; j += 256) atomicAdd(&lc[te[j]], 1);
    __syncthreads();
    if (t == 0){
        int off = NTOK;
        for (int e = 0; e < 8; e++){
            lcur[e]    = off;
            meta[e]    = lc[e];
            meta[16+e] = off;
            meta[32+e] = (lc[e] + BM - 1) / BM;
            off += lc[e];
        }
        meta[8]    = NTOK;      // shared expert
        meta[16+8] = 0;
        meta[32+8] = NTOK / BM;
    }
    __syncthreads();
    for (int j = t; j < NTOK*2; j += 256){
        int e = te[j];
        int p = atomicAdd(&lcur[e], 1);
        tokarr[p] = j >> 1;
        rowof[j]  = p;
    }
}

// MODE 0: H[row] = gelu(Xg @ W1_e^T + b1)   (N=4096=32 nt, K=1024) -> bf16 H
// MODE 1: Y[row] = H @ W2_e^T + b2          (N=1024= 8 nt, K=4096) -> fp32 Y
// XCD-aware schedule: blockIdx = q*8 + xcd. Per XCD, queue = experts in order,
// each contributing NTG nt-columns (nt = xcd + 8*ntg) with all m-tiles
// consecutive -> blocks sharing a B-strip are same-XCD and temporally adjacent
// (L2-resident B after the first m-tile).
template<int MODE>
__global__ __launch_bounds__(256) void gemm_kernel(
    const ushort* __restrict__ Abase,
    const ushort* __restrict__ Wb, const ushort* __restrict__ Wsb,
    const float* __restrict__ brout, const float* __restrict__ bsh,
    const int* __restrict__ meta, const int* __restrict__ tokarr,
    ushort* __restrict__ Hout, float* __restrict__ Yout)
{
    const int xcd = blockIdx.x & 7;
    const int q   = blockIdx.x >> 3;
    const int NTG = (MODE == 0) ? 4 : 1;     // nt-columns per expert per XCD

    int e = -1, r = 0, a0 = 0;
    #pragma unroll
    for (int ee = 0; ee < 9; ee++){
        int w = NTG * meta[32 + ee];
        if (e < 0 && q < a0 + w){ e = ee; r = q - a0; }
        a0 += w;
    }
    if (e < 0) return;
    const int mt_e = meta[32 + e];
    int ntg, mti;
    if (MODE == 0){ ntg = r / mt_e; mti = r - ntg * mt_e; }
    else          { ntg = 0;        mti = r; }
    const int nt   = (MODE == 0) ? (xcd + 8 * ntg) : xcd;
    const int cnt  = meta[e];
    const int base = meta[16 + e];

    const int K = (MODE == 0) ? DM : DF;
    const int N = (MODE == 0) ? DF : DM;
    const ushort* Bp  = (e < 8) ? (Wb + (size_t)e * DF * DM) : Wsb;
    const float* bias = (e < 8) ? (brout + e * N) : bsh;

    __shared__ ushort As[BM * BK];   // unpadded: required by global_load_lds
    __shared__ ushort Bs[BN * BK];

    const int t    = threadIdx.x;
    const int lane = t & 63;
    const int wv   = t >> 6;
    const int wm   = (wv >> 1) * 64;
    const int wn   = (wv & 1) * 64;
    const int lrow = lane & 15;
    const int quad = lane >> 4;
    // column swizzle (16B units): phys_seg = log_seg ^ (row&7)
    const int swz8 = ((lane & 7) ^ (lane >> 3)) * 8;

    const ushort* Ap[4];
    const ushort* Bpp[4];
    ushort* Alds[4];
    ushort* Blds[4];
    #pragma unroll
    for (int i = 0; i < 4; i++){
        int rin = wv * 32 + i * 8 + (lane >> 3);
        int pos = mti * BM + rin;
        int clp = (pos < cnt) ? pos : (cnt - 1);
        if (MODE == 0) Ap[i] = Abase + (size_t)tokarr[base + clp] * DM + swz8;
        else           Ap[i] = Abase + (size_t)(base + clp) * DF + swz8;
        Bpp[i]  = Bp + (size_t)(nt * BN + rin) * K + swz8;
        Alds[i] = &As[(wv * 32 + i * 8) * BK];
        Blds[i] = &Bs[(wv * 32 + i * 8) * BK];
    }

    floatx4 acc[4][4];
    #pragma unroll
    for (int mi = 0; mi < 4; mi++)
        #pragma unroll
        for (int ni = 0; ni < 4; ni++)
            acc[mi][ni] = (floatx4){0.f, 0.f, 0.f, 0.f};

    for (int k0 = 0; k0 < K; k0 += BK){
        __syncthreads();
        #pragma unroll
        for (int i = 0; i < 4; i++){
            GLD16(Ap[i]  + k0, Alds[i]);
            GLD16(Bpp[i] + k0, Blds[i]);
        }
        __syncthreads();   // vmcnt(0) drain + barrier (m97 structure)
        #pragma unroll
        for (int kk = 0; kk < BK; kk += 32){
            short8 af[4], bfr[4];
            #pragma unroll
            for (int mi = 0; mi < 4; mi++){
                int row  = wm + mi * 16 + lrow;
                int phys = ((kk >> 3) + quad) ^ (row & 7);
                af[mi] = *reinterpret_cast<const short8*>(&As[row * BK + phys * 8]);
            }
            #pragma unroll
            for (int ni = 0; ni < 4; ni++){
                int row  = wn + ni * 16 + lrow;
                int phys = ((kk >> 3) + quad) ^ (row & 7);
                bfr[ni] = *reinterpret_cast<const short8*>(&Bs[row * BK + phys * 8]);
            }
            #pragma unroll
            for (int mi = 0; mi < 4; mi++)
                #pragma unroll
                for (int ni = 0; ni < 4; ni++)
                    acc[mi][ni] = __builtin_amdgcn_mfma_f32_16x16x32_bf16(af[mi], bfr[ni], acc[mi][ni], 0, 0, 0);
        }
    }

    // epilogue; C/D: col = lane&15, row = quad*4 + reg  [m89]
    float bv[4];
    #pragma unroll
    for (int ni = 0; ni < 4; ni++) bv[ni] = bias[nt * BN + wn + ni*16 + lrow];

    #pragma unroll
    for (int mi = 0; mi < 4; mi++){
        #pragma unroll
        for (int rg = 0; rg < 4; rg++){
            int s   = wm + mi*16 + quad*4 + rg;
            int pos = mti * BM + s;
            if (pos >= cnt) continue;
            int rr = base + pos;
            if (MODE == 0){
                ushort* hp = Hout + (size_t)rr * DF + nt * BN;
                #pragma unroll
                for (int ni = 0; ni < 4; ni++){
                    float v = acc[mi][ni][rg] + bv[ni];
                    hp[wn + ni*16 + lrow] = f2bf(gelu_tanh(v));
                }
            } else {
                float* yp = Yout + (size_t)rr * DM + nt * BN;
                #pragma unroll
                for (int ni = 0; ni < 4; ni++)
                    yp[wn + ni*16 + lrow] = acc[mi][ni][rg] + bv[ni];
            }
        }
    }
}

// out[t] = SCALE * (Y[t] + g1*Y[r1] + g2*Y[r2])
__global__ __launch_bounds__(256) void combine_kernel(
    const float* __restrict__ Y, const int* __restrict__ rowof,
    const float* __restrict__ tg, float* __restrict__ out)
{
    const int token = blockIdx.x;
    const int d4    = threadIdx.x;
    const float4* Y4 = reinterpret_cast<const float4*>(Y);
    int r1 = rowof[token*2+0], r2 = rowof[token*2+1];
    float g1 = tg[token*2+0],  g2 = tg[token*2+1];
    float4 a = Y4[(size_t)token * 256 + d4];
    float4 b = Y4[(size_t)r1 * 256 + d4];
    float4 c = Y4[(size_t)r2 * 256 + d4];
    float4 o;
    o.x = SCALE_F * (a.x + g1*b.x + g2*c.x);
    o.y = SCALE_F * (a.y + g1*b.y + g2*c.y);
    o.z = SCALE_F * (a.z + g1*b.z + g2*c.z);
    o.w = SCALE_F * (a.w + g1*b.w + g2*c.w);
    reinterpret_cast<float4*>(out)[(size_t)token * 256 + d4] = o;
}

extern "C" void kernel_launch(void* const* d_in, const int* in_sizes, int n_in,
                              void* d_out, int out_size, void* d_ws, size_t ws_size,
                              hipStream_t stream) {
    const float* x   = (const float*)d_in[0];
    const float* wr  = (const float*)d_in[1];
    const float* W1  = (const float*)d_in[2];
    const float* b1  = (const float*)d_in[3];
    const float* W2  = (const float*)d_in[4];
    const float* b2  = (const float*)d_in[5];
    const float* Ws1 = (const float*)d_in[6];
    const float* bs1 = (const float*)d_in[7];
    const float* Ws2 = (const float*)d_in[8];
    const float* bs2 = (const float*)d_in[9];
    float* out = (float*)d_out;

    char* ws = (char*)d_ws;
    size_t off = 0;
    auto wsalloc = [&](size_t bytes) -> char* {
        char* p = ws + off;
        off += (bytes + 255) & ~(size_t)255;
        return p;
    };
    ushort* xb   = (ushort*)wsalloc((size_t)NTOK * DM * 2);
    ushort* w1b  = (ushort*)wsalloc((size_t)8 * DF * DM * 2);
    ushort* w2b  = (ushort*)wsalloc((size_t)8 * DM * DF * 2);
    ushort* ws1b = (ushort*)wsalloc((size_t)DF * DM * 2);
    ushort* ws2b = (ushort*)wsalloc((size_t)DM * DF * 2);
    ushort* H    = (ushort*)wsalloc((size_t)ROWS_TOTAL * DF * 2);
    int*    tokarr = (int*)wsalloc(ROWS_TOTAL * 4);
    int*    rowof  = (int*)wsalloc(NTOK * 2 * 4);
    int*    te     = (int*)wsalloc(NTOK * 2 * 4);
    float*  tg     = (float*)wsalloc(NTOK * 2 * 4);
    int*    meta   = (int*)wsalloc(64 * 4);
    // Y (50.3MB fp32) aliases w1b (67MB): w1b dead after gemm1, Y born in gemm2
    float*  Y = (float*)w1b;

    cvt_all<<<CVT_N4/256, 256, 0, stream>>>(x, W1, W2, Ws1, Ws2,
                                            xb, w1b, w2b, ws1b, ws2b);
    router_kernel<<<NTOK/4, 256, 0, stream>>>(x, wr, te, tg, tokarr);
    plan_kernel<<<1, 256, 0, stream>>>(te, tokarr, rowof, meta);

    // grid = 8 XCD lanes x worst-case per-XCD queue length
    gemm_kernel<0><<<8 * 4 * PMAX, 256, 0, stream>>>(xb, w1b, ws1b, b1, bs1,
        meta, tokarr, H, Y);
    gemm_kernel<1><<<8 * PMAX, 256, 0, stream>>>(H, w2b, ws2b, b2, bs2,
        meta, tokarr, H, Y);

    combine_kernel<<<NTOK, 256, 0, stream>>>(Y, rowof, tg, out);
}